// Round 15
// baseline (54.615 us; speedup 1.0000x reference)
//
#include <hip/hip_runtime.h>

// Deimv2LQE: out = scores + MLP(top4-softmax-stats(pred_corners))
// 262144 rows; per row 132 f32 (4 corners x 33 bins).
// R15: MEASUREMENT ROUND. Kernel 1 = R9 verbatim (best: 32.7us, correct
//   output). Kernel 2 = pure-read probe over the same pc buffer (grid-stride
//   float4 stream, liveness pinned, one float/block to d_ws) to measure the
//   L3-resident READ-ONLY bandwidth ceiling. Theory split:
//   probe ~31us -> 4.3 TB/s ceiling -> R9 IS the roofline (revert+declare);
//   probe ~22us -> ~6 TB/s possible -> rework R9's staging schedule.

#define THREADS 256
#define ROWS 64

typedef float f32x4 __attribute__((ext_vector_type(4), aligned(16)));

__device__ __forceinline__ void sort4d(float& a, float& b, float& c, float& d) {
    float t;
    t = fmaxf(a, b); b = fminf(a, b); a = t;
    t = fmaxf(c, d); d = fminf(c, d); c = t;
    t = fmaxf(a, c); c = fminf(a, c); a = t;
    t = fmaxf(b, d); d = fminf(b, d); b = t;
    t = fmaxf(b, c); c = fminf(b, c); b = t;
}
__device__ __forceinline__ void ins4(float& a, float& b, float& c, float& d,
                                     float x) {
    float t;
    t = fmaxf(a, x); x = fminf(a, x); a = t;
    t = fmaxf(b, x); x = fminf(b, x); b = t;
    t = fmaxf(c, x); x = fminf(c, x); c = t;
    d = fmaxf(d, x);
}
__device__ __forceinline__ void merge4(float& a0, float& a1, float& a2,
                                       float& a3, float b0, float b1,
                                       float b2, float b3) {
    a0 = fmaxf(a0, b3);
    a1 = fmaxf(a1, b2);
    a2 = fmaxf(a2, b1);
    a3 = fmaxf(a3, b0);
    sort4d(a0, a1, a2, a3);
}

__global__ __launch_bounds__(THREADS, 4)
void lqe_kernel(const float* __restrict__ scores,
                const float* __restrict__ pc,
                const float* __restrict__ w1,
                const float* __restrict__ b1,
                const float* __restrict__ w2,
                const float* __restrict__ b2,
                float* __restrict__ out)
{
    __shared__ float sm_stage[ROWS * 132];  // 33792 B; reused for partials
    __shared__ float sm_stat[ROWS * 21];    // 5376 B, stride 21 (odd)

    const int t = threadIdx.x;
    const long long rowBase = (long long)blockIdx.x * ROWS;

    // ---- stage: 2112 float4, fully contiguous & coalesced ----
    {
        const f32x4* __restrict__ src = (const f32x4*)(pc + rowBase * 132);
        f32x4* dst = (f32x4*)sm_stage;
        #pragma unroll
        for (int i = 0; i < 8; ++i) dst[t + i * 256] = src[t + i * 256];
        if (t < 64) dst[2048 + t] = src[2048 + t];
    }
    __syncthreads();

    // ---- corner task t: row = t>>2, corner = t&3; LDS base 33*t ----
    {
        const float* v = sm_stage + t * 33;
        float x[33];
        #pragma unroll
        for (int k = 0; k < 33; ++k) x[k] = v[k];

        float a0 = x[0],  a1 = x[1],  a2 = x[2],  a3 = x[3];
        float c0 = x[8],  c1 = x[9],  c2 = x[10], c3 = x[11];
        float d0 = x[16], d1 = x[17], d2 = x[18], d3 = x[19];
        float e0 = x[24], e1 = x[25], e2 = x[26], e3 = x[27];
        sort4d(a0, a1, a2, a3);
        sort4d(c0, c1, c2, c3);
        sort4d(d0, d1, d2, d3);
        sort4d(e0, e1, e2, e3);
        #pragma unroll
        for (int k = 0; k < 4; ++k) {
            ins4(a0, a1, a2, a3, x[4 + k]);
            ins4(c0, c1, c2, c3, x[12 + k]);
            ins4(d0, d1, d2, d3, x[20 + k]);
            ins4(e0, e1, e2, e3, x[28 + k]);
        }
        ins4(e0, e1, e2, e3, x[32]);
        merge4(a0, a1, a2, a3, c0, c1, c2, c3);
        merge4(d0, d1, d2, d3, e0, e1, e2, e3);
        merge4(a0, a1, a2, a3, d0, d1, d2, d3);
        const float t0 = a0, t1 = a1, t2 = a2, t3 = a3;

        float sa = 0.f, sb = 0.f, sc = 0.f, sd = 0.f;
        #pragma unroll
        for (int k = 0; k < 32; k += 4) {
            sa += __expf(x[k + 0] - t0);
            sb += __expf(x[k + 1] - t0);
            sc += __expf(x[k + 2] - t0);
            sd += __expf(x[k + 3] - t0);
        }
        sa += __expf(x[32] - t0);
        const float inv = 1.0f / ((sa + sb) + (sc + sd));
        const float p0 = inv;
        const float p1 = __expf(t1 - t0) * inv;
        const float p2 = __expf(t2 - t0) * inv;
        const float p3 = __expf(t3 - t0) * inv;
        const float pm = 0.25f * (p0 + p1 + p2 + p3);

        float* sd_ = sm_stat + (t >> 2) * 21 + (t & 3) * 5;
        sd_[0] = p0; sd_[1] = p1; sd_[2] = p2; sd_[3] = p3; sd_[4] = pm;
    }
    __syncthreads();

    // ---- MLP: wave wv computes hidden slice [16wv,16wv+16) for row l ----
    {
        const int l  = t & 63;
        const int wv = __builtin_amdgcn_readfirstlane(t >> 6);  // scalar
        const float* __restrict__ w1s = w1 + wv * 16;
        const float* __restrict__ w2s = w2 + wv * 16;
        const float* __restrict__ b1s = b1 + wv * 16;

        float st[20];
        #pragma unroll
        for (int k = 0; k < 20; ++k) st[k] = sm_stat[l * 21 + k];

        float h[16];
        #pragma unroll
        for (int j = 0; j < 16; ++j) h[j] = b1s[j];
        #pragma unroll
        for (int k = 0; k < 20; ++k) {
            #pragma unroll
            for (int j = 0; j < 16; ++j)
                h[j] = fmaf(st[k], w1s[k * 64 + j], h[j]);
        }
        float acc0 = 0.f, acc1 = 0.f, acc2 = 0.f, acc3 = 0.f;
        #pragma unroll
        for (int j = 0; j < 16; j += 4) {
            acc0 = fmaf(fmaxf(h[j + 0], 0.f), w2s[j + 0], acc0);
            acc1 = fmaf(fmaxf(h[j + 1], 0.f), w2s[j + 1], acc1);
            acc2 = fmaf(fmaxf(h[j + 2], 0.f), w2s[j + 2], acc2);
            acc3 = fmaf(fmaxf(h[j + 3], 0.f), w2s[j + 3], acc3);
        }
        sm_stage[wv * 64 + l] = (acc0 + acc1) + (acc2 + acc3);
    }
    __syncthreads();

    if (t < 64) {
        const float r = (sm_stage[t] + sm_stage[64 + t]) +
                        (sm_stage[128 + t] + sm_stage[192 + t]);
        out[rowBase + t] = scores[rowBase + t] + r + b2[0];
    }
}

// ---- pure-read probe: measures the L3-resident read-only ceiling ----
__global__ __launch_bounds__(THREADS)
void read_probe(const f32x4* __restrict__ src, float* __restrict__ ws,
                int n4)
{
    const int stride = gridDim.x * THREADS;
    int i = blockIdx.x * THREADS + threadIdx.x;
    f32x4 s0 = {0,0,0,0}, s1 = {0,0,0,0}, s2 = {0,0,0,0}, s3 = {0,0,0,0};
    for (; i + 3 * stride < n4; i += 4 * stride) {
        s0 += src[i];
        s1 += src[i + stride];
        s2 += src[i + 2 * stride];
        s3 += src[i + 3 * stride];
    }
    for (; i < n4; i += stride) s0 += src[i];
    float s = (s0.x + s0.y + s0.z + s0.w) + (s1.x + s1.y + s1.z + s1.w) +
              (s2.x + s2.y + s2.z + s2.w) + (s3.x + s3.y + s3.z + s3.w);
    asm volatile("" :: "v"(s));                 // keep every lane's loads live
    if (threadIdx.x == 0) ws[blockIdx.x] = s;   // deterministic, scratch-only
}

extern "C" void kernel_launch(void* const* d_in, const int* in_sizes, int n_in,
                              void* d_out, int out_size, void* d_ws, size_t ws_size,
                              hipStream_t stream) {
    const float* scores = (const float*)d_in[0];
    const float* pc     = (const float*)d_in[1];
    const float* w1     = (const float*)d_in[2];
    const float* b1     = (const float*)d_in[3];
    const float* w2     = (const float*)d_in[4];
    const float* b2     = (const float*)d_in[5];
    float* out = (float*)d_out;

    const int rows = out_size;          // 262144
    const int blocks = rows / ROWS;     // 4096
    lqe_kernel<<<blocks, THREADS, 0, stream>>>(scores, pc, w1, b1, w2, b2, out);

    // measurement rider: pure-read stream over the same 138.4 MB buffer
    const int PROBE_BLOCKS = 2048;
    if (ws_size >= PROBE_BLOCKS * sizeof(float)) {
        const int n4 = in_sizes[1] / 4;     // 8,650,752 float4
        read_probe<<<PROBE_BLOCKS, THREADS, 0, stream>>>(
            (const f32x4*)pc, (float*)d_ws, n4);
    }
}

// Round 16
// 37.501 us; speedup vs baseline: 1.4563x; 1.4563x over previous
//
#include <hip/hip_runtime.h>

// Deimv2LQE: out = scores + MLP(top4-softmax-stats(pred_corners))
// 262144 rows; per row 132 f32 (4 corners x 33 bins).
// R16: 2-tile register-prefetch pipeline. R15's probe measured 6.3 TB/s
//   read-only (L3-resident) vs R9's effective 4.3 -> R9 serializes
//   mem & compute. Here: issue tile0 AND tile1 loads up front (rb held in
//   32 VGPRs), ds_write tile0 (counted vmcnt; tile1 stays in flight),
//   full tile0 compute hides tile1's round trip, then ds_write tile1.
//   ALL mid-kernel barriers are lgkmcnt-only (no vmcnt drain).
//   Compute bodies = R9 (ILP top-4, 4-acc exp, wave-split s_load MLP).

#define THREADS 256

typedef float f32x4 __attribute__((ext_vector_type(4), aligned(16)));

// LDS-only barrier: does NOT drain vmcnt (prefetch stays in flight)
#define BAR_LGKM() asm volatile("s_waitcnt lgkmcnt(0)\n\ts_barrier" ::: "memory")

__device__ __forceinline__ void sort4d(float& a, float& b, float& c, float& d) {
    float t;
    t = fmaxf(a, b); b = fminf(a, b); a = t;
    t = fmaxf(c, d); d = fminf(c, d); c = t;
    t = fmaxf(a, c); c = fminf(a, c); a = t;
    t = fmaxf(b, d); d = fminf(b, d); b = t;
    t = fmaxf(b, c); c = fminf(b, c); b = t;
}
__device__ __forceinline__ void ins4(float& a, float& b, float& c, float& d,
                                     float x) {
    float t;
    t = fmaxf(a, x); x = fminf(a, x); a = t;
    t = fmaxf(b, x); x = fminf(b, x); b = t;
    t = fmaxf(c, x); x = fminf(c, x); c = t;
    d = fmaxf(d, x);
}
__device__ __forceinline__ void merge4(float& a0, float& a1, float& a2,
                                       float& a3, float b0, float b1,
                                       float b2, float b3) {
    a0 = fmaxf(a0, b3);
    a1 = fmaxf(a1, b2);
    a2 = fmaxf(a2, b1);
    a3 = fmaxf(a3, b0);
    sort4d(a0, a1, a2, a3);
}

__device__ __forceinline__ void corner_phase(const float* __restrict__ stage,
                                             float* __restrict__ stat, int t) {
    const float* v = stage + t * 33;   // odd stride -> conflict-free
    float x[33];
    #pragma unroll
    for (int k = 0; k < 33; ++k) x[k] = v[k];

    float a0 = x[0],  a1 = x[1],  a2 = x[2],  a3 = x[3];
    float c0 = x[8],  c1 = x[9],  c2 = x[10], c3 = x[11];
    float d0 = x[16], d1 = x[17], d2 = x[18], d3 = x[19];
    float e0 = x[24], e1 = x[25], e2 = x[26], e3 = x[27];
    sort4d(a0, a1, a2, a3);
    sort4d(c0, c1, c2, c3);
    sort4d(d0, d1, d2, d3);
    sort4d(e0, e1, e2, e3);
    #pragma unroll
    for (int k = 0; k < 4; ++k) {
        ins4(a0, a1, a2, a3, x[4 + k]);
        ins4(c0, c1, c2, c3, x[12 + k]);
        ins4(d0, d1, d2, d3, x[20 + k]);
        ins4(e0, e1, e2, e3, x[28 + k]);
    }
    ins4(e0, e1, e2, e3, x[32]);
    merge4(a0, a1, a2, a3, c0, c1, c2, c3);
    merge4(d0, d1, d2, d3, e0, e1, e2, e3);
    merge4(a0, a1, a2, a3, d0, d1, d2, d3);
    const float t0 = a0, t1 = a1, t2 = a2, t3 = a3;

    float sa = 0.f, sb = 0.f, sc = 0.f, sd = 0.f;
    #pragma unroll
    for (int k = 0; k < 32; k += 4) {
        sa += __expf(x[k + 0] - t0);
        sb += __expf(x[k + 1] - t0);
        sc += __expf(x[k + 2] - t0);
        sd += __expf(x[k + 3] - t0);
    }
    sa += __expf(x[32] - t0);
    const float inv = 1.0f / ((sa + sb) + (sc + sd));
    const float p0 = inv;
    const float p1 = __expf(t1 - t0) * inv;
    const float p2 = __expf(t2 - t0) * inv;
    const float p3 = __expf(t3 - t0) * inv;
    const float pm = 0.25f * (p0 + p1 + p2 + p3);

    float* sd_ = stat + (t >> 2) * 21 + (t & 3) * 5;
    sd_[0] = p0; sd_[1] = p1; sd_[2] = p2; sd_[3] = p3; sd_[4] = pm;
}

__device__ __forceinline__ void mlp_phase(const float* __restrict__ stat,
                                          float* __restrict__ part, int t,
                                          const float* __restrict__ w1,
                                          const float* __restrict__ b1,
                                          const float* __restrict__ w2) {
    const int l  = t & 63;
    const int wv = __builtin_amdgcn_readfirstlane(t >> 6);   // scalar
    const float* __restrict__ w1s = w1 + wv * 16;
    const float* __restrict__ w2s = w2 + wv * 16;
    const float* __restrict__ b1s = b1 + wv * 16;

    float st[20];
    #pragma unroll
    for (int k = 0; k < 20; ++k) st[k] = stat[l * 21 + k];

    float h[16];
    #pragma unroll
    for (int j = 0; j < 16; ++j) h[j] = b1s[j];
    #pragma unroll
    for (int k = 0; k < 20; ++k) {
        #pragma unroll
        for (int j = 0; j < 16; ++j)
            h[j] = fmaf(st[k], w1s[k * 64 + j], h[j]);
    }
    float acc0 = 0.f, acc1 = 0.f, acc2 = 0.f, acc3 = 0.f;
    #pragma unroll
    for (int j = 0; j < 16; j += 4) {
        acc0 = fmaf(fmaxf(h[j + 0], 0.f), w2s[j + 0], acc0);
        acc1 = fmaf(fmaxf(h[j + 1], 0.f), w2s[j + 1], acc1);
        acc2 = fmaf(fmaxf(h[j + 2], 0.f), w2s[j + 2], acc2);
        acc3 = fmaf(fmaxf(h[j + 3], 0.f), w2s[j + 3], acc3);
    }
    part[wv * 64 + l] = (acc0 + acc1) + (acc2 + acc3);
}

__global__ __launch_bounds__(THREADS, 4)
void lqe_kernel(const float* __restrict__ scores,
                const float* __restrict__ pc,
                const float* __restrict__ w1,
                const float* __restrict__ b1,
                const float* __restrict__ w2,
                const float* __restrict__ b2,
                float* __restrict__ out)
{
    __shared__ float smStage[64 * 132];   // 33792 B, reused by both tiles
    __shared__ float smStat[64 * 21];     // 5376 B
    __shared__ float smPart[256];         // 1024 B

    const int t = threadIdx.x;
    const long long rowBase = (long long)blockIdx.x * 128;
    const float b2v = b2[0];

    float sc0 = 0.f, sc1 = 0.f;
    if (t < 64) {
        sc0 = scores[rowBase + t];
        sc1 = scores[rowBase + 64 + t];
    }

    // ---- issue BOTH tiles' loads up front (18 outstanding max) ----
    const f32x4* __restrict__ s0 = (const f32x4*)(pc + rowBase * 132);
    const f32x4* __restrict__ s1 = (const f32x4*)(pc + (rowBase + 64) * 132);
    f32x4 ra[8], rb[8], taA = {0,0,0,0}, tbB = {0,0,0,0};
    #pragma unroll
    for (int i = 0; i < 8; ++i) ra[i] = s0[t + i * 256];
    if (t < 64) taA = s0[2048 + t];
    #pragma unroll
    for (int i = 0; i < 8; ++i) rb[i] = s1[t + i * 256];
    if (t < 64) tbB = s1[2048 + t];
    __builtin_amdgcn_sched_barrier(0);   // pin load issue before everything

    // ---- write tile0 (counted vmcnt: rb stays in flight) ----
    {
        f32x4* dst = (f32x4*)smStage;
        #pragma unroll
        for (int i = 0; i < 8; ++i) dst[t + i * 256] = ra[i];
        if (t < 64) dst[2048 + t] = taA;
    }
    BAR_LGKM();                          // tile0 visible; rb airborne

    // ---- tile0 compute (hides tile1's memory round trip) ----
    corner_phase(smStage, smStat, t);
    BAR_LGKM();
    mlp_phase(smStat, smPart, t, w1, b1, w2);
    BAR_LGKM();
    if (t < 64)
        out[rowBase + t] =
            sc0 + (smPart[t] + smPart[64 + t]) +
                  (smPart[128 + t] + smPart[192 + t]) + b2v;

    // ---- write tile1 (rb should have landed under tile0 compute) ----
    {
        f32x4* dst = (f32x4*)smStage;
        #pragma unroll
        for (int i = 0; i < 8; ++i) dst[t + i * 256] = rb[i];
        if (t < 64) dst[2048 + t] = tbB;
    }
    BAR_LGKM();

    // ---- tile1 compute ----
    corner_phase(smStage, smStat, t);
    BAR_LGKM();
    mlp_phase(smStat, smPart, t, w1, b1, w2);
    BAR_LGKM();
    if (t < 64)
        out[rowBase + 64 + t] =
            sc1 + (smPart[t] + smPart[64 + t]) +
                  (smPart[128 + t] + smPart[192 + t]) + b2v;
}

extern "C" void kernel_launch(void* const* d_in, const int* in_sizes, int n_in,
                              void* d_out, int out_size, void* d_ws, size_t ws_size,
                              hipStream_t stream) {
    const float* scores = (const float*)d_in[0];
    const float* pc     = (const float*)d_in[1];
    const float* w1     = (const float*)d_in[2];
    const float* b1     = (const float*)d_in[3];
    const float* w2     = (const float*)d_in[4];
    const float* b2     = (const float*)d_in[5];
    float* out = (float*)d_out;

    const int rows = out_size;          // 262144
    const int blocks = rows / 128;      // 2048
    lqe_kernel<<<blocks, THREADS, 0, stream>>>(scores, pc, w1, b1, w2, b2, out);
}